// Round 1
// baseline (38.882 us; speedup 1.0000x reference)
//
#include <hip/hip_runtime.h>
#include <stdint.h>

#define N_IMG 16
#define H_DIM 512
#define W_DIM 512
#define PADR 15
#define BAND 16                 // output rows per block
#define HALO (BAND + 2 * PADR)  // 46 staged bitmap rows
#define WPR 18                  // 32-bit words per bitmap row: 1 pad + 16 data + 1 pad

// ws layout: part = 512 blocks * 5 f32 : [bce,in0,in1,un0,un1] per block

// ---------------------------------------------------------------------------
// Mega kernel: fused 31x31 box-sum (ballot/popcount) + elementwise loss.
// Block = 512 threads (one per col) x 16 output rows of one image.
// 128-VGPR budget (launch_bounds min-waves=4): grid is 2 blocks/CU anyway,
// so the extra registers buy MLP (46 target + 32 pred loads in flight)
// without losing occupancy.
// ---------------------------------------------------------------------------
__global__ __launch_bounds__(512, 4) void mega_kernel(const int* __restrict__ target,
                                                      const float* __restrict__ pred,
                                                      float* __restrict__ part) {
    __shared__ uint32_t B[HALO][WPR];            // 31-bit-window bitmap, 32-bit words
    const int tid = threadIdx.x;                 // = col
    const int band = blockIdx.x;                 // 0..31
    const int n = blockIdx.y;
    const int r0 = band * BAND;
    const int col = tid;
    const int* __restrict__ tg = target + (size_t)n * H_DIM * W_DIM;

    if (tid < 2 * HALO) B[tid >> 1][(tid & 1) ? (WPR - 1) : 0] = 0u;

    // ---- phase A: halo target loads (independent, all in flight) ----
    int tv[HALO];
#pragma unroll
    for (int i = 0; i < HALO; ++i) {
        const int r = r0 - PADR + i;             // wave-uniform validity
        tv[i] = (r >= 0 && r < H_DIM) ? tg[(size_t)r * W_DIM + col] : 0;
    }

    // ---- pred loads issued EARLY: stay outstanding across ballots+barrier+phaseB
    const size_t img = (size_t)n * H_DIM * W_DIM;
    const float* __restrict__ p0 = pred + img * 2 + (size_t)r0 * W_DIM + col;
    const float* __restrict__ p1 = p0 + (size_t)H_DIM * W_DIM;
    float x0[BAND], x1[BAND];
#pragma unroll
    for (int rr = 0; rr < BAND; ++rr) {
        x0[rr] = p0[rr * W_DIM];
        x1[rr] = p1[rr * W_DIM];
    }

    // ---- ballots -> LDS bitmaps (32-bit halves) ----
#pragma unroll
    for (int i = 0; i < HALO; ++i) {
        const unsigned long long bal = __ballot(tv[i] == 1);
        const uint32_t half = (tid & 32) ? (uint32_t)(bal >> 32) : (uint32_t)bal;
        if ((tid & 31) == 0) B[i][1 + (tid >> 5)] = half;
    }
    __syncthreads();

    // ---- phase B: 31-bit window popcount per halo row + m bits ----
    // data bit for col c lives at bitmap bit 32+c; window starts at b = c+17
    const int b = col + (32 - PADR);
    const int q = b >> 5, s = b & 31;
    uint32_t h[HALO];
    uint32_t mbits = 0;
#pragma unroll
    for (int i = 0; i < HALO; ++i) {
        const uint32_t lo = B[i][q];
        const uint32_t hi = B[i][q + 1];
        const uint32_t val =
            (uint32_t)((((uint64_t)hi << 32) | lo) >> s) & 0x7FFFFFFFu;  // v_alignbit
        h[i] = (uint32_t)__popc(val);
        if (i >= PADR && i < PADR + BAND)
            mbits |= ((val >> PADR) & 1u) << (i - PADR);  // center bit = window bit 15
    }
    uint32_t run = 0;
#pragma unroll
    for (int i = 0; i < 31; ++i) run += h[i];

    // ---- phase C: loss math (pred values already resident in x0/x1) ----
    const int cntw = min(col + PADR, W_DIM - 1) - max(col - PADR, 0) + 1;
    const float inv961 = 1.0f / 961.0f;
    float bce = 0.f, in0 = 0.f, in1 = 0.f, un0 = 0.f, un1 = 0.f;

#pragma unroll
    for (int rr = 0; rr < BAND; ++rr) {
        const int r = r0 + rr;
        const int cnth = min(r + PADR, H_DIM - 1) - max(r - PADR, 0) + 1;
        const float cnt = (float)(cnth * cntw);
        const float m1 = (float)((mbits >> rr) & 1u);
        const float m0 = 1.0f - m1;
        const float V = (float)run;
        const float box1 = V * inv961;
        const float box0 = (cnt - V) * inv961;
        const float w1f = 1.0f + 5.0f * fabsf(box1 - m1);
        const float w0f = 1.0f + 5.0f * fabsf(box0 - m0);
        {   // channel 0
            const float x = x0[rr];
            const float t = __expf(-fabsf(x));
            const float inv = 1.0f / (1.0f + t);
            const float p = (x >= 0.f) ? inv : t * inv;
            bce += fmaxf(x, 0.f) - x * m0 + __logf(1.0f + t);
            in0 += p * m0 * w0f;
            un0 += (p + m0) * w0f;
        }
        {   // channel 1
            const float x = x1[rr];
            const float t = __expf(-fabsf(x));
            const float inv = 1.0f / (1.0f + t);
            const float p = (x >= 0.f) ? inv : t * inv;
            bce += fmaxf(x, 0.f) - x * m1 + __logf(1.0f + t);
            in1 += p * m1 * w1f;
            un1 += (p + m1) * w1f;
        }
        if (rr < BAND - 1) run += h[rr + 31] - h[rr];   // slide vertical window
    }

    // ---- block reduction: 5 values -> plain store to private slot ----
    __shared__ float red[8 * 5];
    const int lane = tid & 63, wv = tid >> 6;
    float v[5] = {bce, in0, in1, un0, un1};
#pragma unroll
    for (int k = 0; k < 5; ++k)
#pragma unroll
        for (int off = 32; off > 0; off >>= 1)
            v[k] += __shfl_down(v[k], off);
    if (lane == 0)
#pragma unroll
        for (int k = 0; k < 5; ++k) red[wv * 5 + k] = v[k];
    __syncthreads();
    if (tid == 0) {
        float s2[5];
#pragma unroll
        for (int k = 0; k < 5; ++k) {
            s2[k] = red[k];
            for (int w2 = 1; w2 < 8; ++w2) s2[k] += red[w2 * 5 + k];
        }
        float* p = part + (size_t)(n * 32 + band) * 5;
#pragma unroll
        for (int k = 0; k < 5; ++k) p[k] = s2[k];
    }
}

// ---------------------------------------------------------------------------
// Finalize: reduce 512 block-partials -> out[0]. One block.
// 16 threads per image; each accumulates 2 partial rows.
// ---------------------------------------------------------------------------
__global__ __launch_bounds__(256) void finalize_kernel(const float* __restrict__ part,
                                                       float* __restrict__ out) {
    const int tid = threadIdx.x;   // 0..255
    const int n = tid >> 4;        // image
    const int i = tid & 15;
    float bce = 0.f, in0 = 0.f, in1 = 0.f, un0 = 0.f, un1 = 0.f;
#pragma unroll
    for (int j = 0; j < 2; ++j) {
        const float* p = part + (size_t)(n * 32 + j * 16 + i) * 5;
        bce += p[0]; in0 += p[1]; in1 += p[2]; un0 += p[3]; un1 += p[4];
    }
#pragma unroll
    for (int off = 8; off > 0; off >>= 1) {
        bce += __shfl_xor(bce, off, 16);
        in0 += __shfl_xor(in0, off, 16);
        in1 += __shfl_xor(in1, off, 16);
        un0 += __shfl_xor(un0, off, 16);
        un1 += __shfl_xor(un1, off, 16);
    }
    __shared__ float fb[16], fw[16];
    if (i == 0) {
        fb[n] = bce;
        fw[n] = (1.0f - (in0 + 1.0f) / (un0 - in0 + 1.0f)) +
                (1.0f - (in1 + 1.0f) / (un1 - in1 + 1.0f));
    }
    __syncthreads();
    if (tid == 0) {
        float sb = 0.f, sw = 0.f;
#pragma unroll
        for (int k = 0; k < 16; ++k) { sb += fb[k]; sw += fw[k]; }
        out[0] = sb / 8388608.0f + sw * (1.0f / 32.0f);  // 16*2*512*512 ; 32 (n,c) pairs
    }
}

extern "C" void kernel_launch(void* const* d_in, const int* in_sizes, int n_in,
                              void* d_out, int out_size, void* d_ws, size_t ws_size,
                              hipStream_t stream) {
    const float* pred = (const float*)d_in[0];
    const int* target = (const int*)d_in[1];
    float* part = (float*)d_ws;

    dim3 grid(H_DIM / BAND, N_IMG);
    mega_kernel<<<grid, 512, 0, stream>>>(target, pred, part);
    finalize_kernel<<<1, 256, 0, stream>>>(part, (float*)d_out);
}

// Round 2
// 27.974 us; speedup vs baseline: 1.3899x; 1.3899x over previous
//
#include <hip/hip_runtime.h>
#include <stdint.h>

#define N_IMG 16
#define H_DIM 512
#define W_DIM 512
#define PADR 15
#define BAND 8                  // output rows per mega block
#define HALO (BAND + 2 * PADR)  // 38 staged bitmap rows
#define WPR 18                  // 32-bit words per bitmap row: 1 pad + 16 data + 1 pad
#define NBANDS (H_DIM / BAND)   // 64
#define WROW (W_DIM / 32)       // 16 data words per row

// ws layout:
//   part  @ 0      : 1024 blocks * 5 f32  [bce,in0,in1,un0,un1]
//   bm    @ 32 KiB : uint32 bm[N][512][16]  (bit c&31 of word c>>5 = target==1)

// ---------------------------------------------------------------------------
// Stage 1: target -> bit-plane. One block per image row; 1 ballot per 64 cols.
// Memory-bound: 16.8 MB read, 0.5 MB written, coalesced 4B/lane.
// ---------------------------------------------------------------------------
__global__ __launch_bounds__(512) void bitmap_kernel(const int* __restrict__ target,
                                                     uint32_t* __restrict__ bm) {
    const int tid = threadIdx.x;
    const size_t idx = (size_t)blockIdx.x * 512 + tid;  // n*512*512 + r*512 + c
    const int t = target[idx];
    const unsigned long long bal = __ballot(t == 1);
    if ((tid & 31) == 0)
        bm[idx >> 5] = (tid & 32) ? (uint32_t)(bal >> 32) : (uint32_t)bal;
}

// ---------------------------------------------------------------------------
// Stage 2: fused 31x31 box-sum (popcount over bit-plane) + elementwise loss.
// Block = 512 threads (one per col) x 8 output rows. Grid 64x16 = 1024 blocks
// -> 4 blocks/CU, 32 waves/CU. No h[] array: sliding-window popcounts are
// recomputed from LDS (trades ~14 popc chains for ~38 VGPRs -> fits 64-VGPR
// budget of __launch_bounds__(512,8)).
// ---------------------------------------------------------------------------
__global__ __launch_bounds__(512, 8) void mega_kernel(const uint32_t* __restrict__ bm,
                                                      const float* __restrict__ pred,
                                                      float* __restrict__ part) {
    __shared__ uint32_t B[HALO][WPR];
    const int tid = threadIdx.x;                 // = col
    const int band = blockIdx.x;                 // 0..63
    const int n = blockIdx.y;
    const int r0 = band * BAND;
    const int col = tid;

    // ---- bitmap halo staging: 38 rows x 16 words = 608 loads, 2 per thread ----
    const uint32_t* __restrict__ bmn = bm + (size_t)n * H_DIM * WROW;
    const int hr0 = tid >> 4, wi = tid & 15;     // task 0: t = tid
    const int ra = r0 - PADR + hr0;
    uint32_t w0 = 0, w1 = 0;
    if (ra >= 0 && ra < H_DIM) w0 = bmn[ra * WROW + wi];
    const int hr1 = hr0 + 32;                    // task 1: t = tid + 512 (tid < 96)
    const int rb = r0 - PADR + hr1;
    if (tid < 96 && rb >= 0 && rb < H_DIM) w1 = bmn[rb * WROW + wi];

    // ---- pred loads issued early: outstanding across staging+barrier+popcounts
    const size_t img = (size_t)n * H_DIM * W_DIM;
    const float* __restrict__ p0 = pred + img * 2 + (size_t)r0 * W_DIM + col;
    const float* __restrict__ p1 = p0 + (size_t)H_DIM * W_DIM;
    float x0[BAND], x1[BAND];
#pragma unroll
    for (int rr = 0; rr < BAND; ++rr) {
        x0[rr] = p0[rr * W_DIM];
        x1[rr] = p1[rr * W_DIM];
    }

    // ---- LDS writes (wait only on bitmap loads; pred stays in flight) ----
    if (tid < 2 * HALO) B[tid >> 1][(tid & 1) ? (WPR - 1) : 0] = 0u;
    B[hr0][1 + wi] = w0;
    if (tid < 96) B[hr1][1 + wi] = w1;
    __syncthreads();

    // ---- 31-bit window popcount helper (broadcast LDS reads, conflict-free)
    const int b = col + (32 - PADR);             // window start bit (word 0 = pad)
    const int q = b >> 5, s = b & 31;
    auto wpop = [&](int i) -> uint32_t {
        const uint32_t lo = B[i][q];
        const uint32_t hi = B[i][q + 1];
        const uint32_t val =
            (uint32_t)((((uint64_t)hi << 32) | lo) >> s) & 0x7FFFFFFFu;  // v_alignbit
        return val;
    };

    // ---- initial vertical window (halo rows 0..30) + center-bit mask ----
    uint32_t run = 0, mbits = 0;
#pragma unroll
    for (int i = 0; i < 31; ++i) {
        const uint32_t val = wpop(i);
        run += (uint32_t)__popc(val);
        if (i >= PADR && i < PADR + BAND)
            mbits |= ((val >> PADR) & 1u) << (i - PADR);  // center bit = window bit 15
    }

    // ---- loss math ----
    const int cntw = min(col + PADR, W_DIM - 1) - max(col - PADR, 0) + 1;
    const float inv961 = 1.0f / 961.0f;
    float bce = 0.f, in0 = 0.f, in1 = 0.f, un0 = 0.f, un1 = 0.f;

#pragma unroll
    for (int rr = 0; rr < BAND; ++rr) {
        const int r = r0 + rr;
        const int cnth = min(r + PADR, H_DIM - 1) - max(r - PADR, 0) + 1;
        const float cnt = (float)(cnth * cntw);
        const float m1 = (float)((mbits >> rr) & 1u);
        const float m0 = 1.0f - m1;
        const float V = (float)run;
        const float box1 = V * inv961;
        const float box0 = (cnt - V) * inv961;
        const float w1f = 1.0f + 5.0f * fabsf(box1 - m1);
        const float w0f = 1.0f + 5.0f * fabsf(box0 - m0);
        {   // channel 0
            const float x = x0[rr];
            const float t = __expf(-fabsf(x));
            const float inv = 1.0f / (1.0f + t);
            const float p = (x >= 0.f) ? inv : t * inv;
            bce += fmaxf(x, 0.f) - x * m0 + __logf(1.0f + t);
            in0 += p * m0 * w0f;
            un0 += (p + m0) * w0f;
        }
        {   // channel 1
            const float x = x1[rr];
            const float t = __expf(-fabsf(x));
            const float inv = 1.0f / (1.0f + t);
            const float p = (x >= 0.f) ? inv : t * inv;
            bce += fmaxf(x, 0.f) - x * m1 + __logf(1.0f + t);
            in1 += p * m1 * w1f;
            un1 += (p + m1) * w1f;
        }
        if (rr < BAND - 1)   // slide vertical window: recompute from LDS (no h[])
            run += (uint32_t)__popc(wpop(rr + 31)) - (uint32_t)__popc(wpop(rr));
    }

    // ---- block reduction: 5 values -> plain store to private slot ----
    __shared__ float red[8 * 5];
    const int lane = tid & 63, wv = tid >> 6;
    float v[5] = {bce, in0, in1, un0, un1};
#pragma unroll
    for (int k = 0; k < 5; ++k)
#pragma unroll
        for (int off = 32; off > 0; off >>= 1)
            v[k] += __shfl_down(v[k], off);
    if (lane == 0)
#pragma unroll
        for (int k = 0; k < 5; ++k) red[wv * 5 + k] = v[k];
    __syncthreads();
    if (tid == 0) {
        float s2[5];
#pragma unroll
        for (int k = 0; k < 5; ++k) {
            s2[k] = red[k];
            for (int w2 = 1; w2 < 8; ++w2) s2[k] += red[w2 * 5 + k];
        }
        float* p = part + (size_t)(n * NBANDS + band) * 5;
#pragma unroll
        for (int k = 0; k < 5; ++k) p[k] = s2[k];
    }
}

// ---------------------------------------------------------------------------
// Finalize: reduce 1024 block-partials -> out[0]. One block.
// 16 threads per image; each accumulates 4 partial rows.
// ---------------------------------------------------------------------------
__global__ __launch_bounds__(256) void finalize_kernel(const float* __restrict__ part,
                                                       float* __restrict__ out) {
    const int tid = threadIdx.x;   // 0..255
    const int n = tid >> 4;        // image
    const int i = tid & 15;
    float bce = 0.f, in0 = 0.f, in1 = 0.f, un0 = 0.f, un1 = 0.f;
#pragma unroll
    for (int j = 0; j < 4; ++j) {
        const float* p = part + (size_t)(n * NBANDS + j * 16 + i) * 5;
        bce += p[0]; in0 += p[1]; in1 += p[2]; un0 += p[3]; un1 += p[4];
    }
#pragma unroll
    for (int off = 8; off > 0; off >>= 1) {
        bce += __shfl_xor(bce, off, 16);
        in0 += __shfl_xor(in0, off, 16);
        in1 += __shfl_xor(in1, off, 16);
        un0 += __shfl_xor(un0, off, 16);
        un1 += __shfl_xor(un1, off, 16);
    }
    __shared__ float fb[16], fw[16];
    if (i == 0) {
        fb[n] = bce;
        fw[n] = (1.0f - (in0 + 1.0f) / (un0 - in0 + 1.0f)) +
                (1.0f - (in1 + 1.0f) / (un1 - in1 + 1.0f));
    }
    __syncthreads();
    if (tid == 0) {
        float sb = 0.f, sw = 0.f;
#pragma unroll
        for (int k = 0; k < 16; ++k) { sb += fb[k]; sw += fw[k]; }
        out[0] = sb / 8388608.0f + sw * (1.0f / 32.0f);  // 16*2*512*512 ; 32 (n,c) pairs
    }
}

extern "C" void kernel_launch(void* const* d_in, const int* in_sizes, int n_in,
                              void* d_out, int out_size, void* d_ws, size_t ws_size,
                              hipStream_t stream) {
    const float* pred = (const float*)d_in[0];
    const int* target = (const int*)d_in[1];
    float* part = (float*)d_ws;
    uint32_t* bm = (uint32_t*)((char*)d_ws + 32768);

    bitmap_kernel<<<N_IMG * H_DIM, 512, 0, stream>>>(target, bm);
    dim3 grid(NBANDS, N_IMG);
    mega_kernel<<<grid, 512, 0, stream>>>(bm, pred, part);
    finalize_kernel<<<1, 256, 0, stream>>>(part, (float*)d_out);
}